// Round 3
// baseline (700.910 us; speedup 1.0000x reference)
//
#include <hip/hip_runtime.h>
#include <cstdint>
#include <cstddef>

// ExllamaLinear: out[M,N] = f16( f16( x[M,K] @ ((q - z) * s)[K,N] ) + bias )
// M = 4096, K = 4096, N = 11008, group 128 along K. fp16 tensors stored f32.
//
// R8: LDS-pipe-bound fix (R7 accounting: LDS 2816 cyc/tile > MFMA 2061):
//   - B operand streamed global->REGISTERS (unswizzled workspace), never
//     touches LDS. LDS traffic/tile: 2816 -> ~1790 cyc (< MFMA 2061).
//   - A through LDS, 4-buffer ring (4 x 32KB = 128KB), staged 3 tiles ahead
//     via global_load_lds; per-tile counted VMW(4) guards loads issued >= 2
//     windows earlier (no stall).
//   - 2 barriers/K-tile only (P2-end producer-WAR, P3-end consumer-RAW);
//     waves skew across P3..P2 -> cross-wave LDS/MFMA overlap; setprio(1)
//     around MFMA now has a real role split to arbitrate.
//   - B frags are plain loads: compiler emits counted vmcnt/lgkmcnt before
//     each MFMA operand use (no rule-18 hazard).

typedef unsigned short u16;
typedef u16    u16x8  __attribute__((ext_vector_type(8)));
typedef __bf16 bfv8   __attribute__((ext_vector_type(8)));
typedef float  f32x4  __attribute__((ext_vector_type(4)));

#define K_DIM 4096
#define N_DIM 11008
#define GS    128
#define KT64  (K_DIM / 64)   // 64 k-tiles of 64
#define LSTR  72             // fused-fallback padded LDS stride

__device__ __forceinline__ u16 f2bf(float f) {  // RTNE f32 -> bf16 bits
  union { float f; uint32_t u; } v;
  v.f = f;
  uint32_t u = v.u + 0x7FFFu + ((v.u >> 16) & 1u);
  return (u16)(u >> 16);
}
__device__ __forceinline__ float f16r(float v) {  // fp16 round-trip (RTNE)
  return (float)(_Float16)v;
}
__device__ __forceinline__ void async_load16(const u16* g, u16* l) {
  __builtin_amdgcn_global_load_lds(
      (const __attribute__((address_space(1))) uint32_t*)g,
      (__attribute__((address_space(3))) uint32_t*)l, 16, 0, 0);
}

// ---------------------------------------------------------------------------
// Pre-pass A: x f32 -> bf16 bits, [128][64] tiles, XOR-swizzled granules
// (LDS-destined). One block per (kt, mt); writes sequential 16B granules.
// ---------------------------------------------------------------------------
__global__ __launch_bounds__(256) void convert_x_tiled(
    const float* __restrict__ x, u16* __restrict__ xb) {
  const int kt = blockIdx.x, mt = blockIdx.y;
  const int k0 = kt * 64, m0 = mt * 128;
  u16* dst = xb + ((size_t)(mt * KT64 + kt)) * 8192;
#pragma unroll
  for (int i = 0; i < 4; ++i) {
    const int g  = i * 256 + threadIdx.x;
    const int nl = g >> 3;
    const int cg = (g & 7) ^ (nl & 7);
    const float* sp = x + (size_t)(m0 + nl) * K_DIM + (k0 + cg * 8);
    const f32x4 p = *(const f32x4*)sp;
    const f32x4 q = *(const f32x4*)(sp + 4);
    u16x8 o;
#pragma unroll
    for (int t = 0; t < 4; ++t) { o[t] = f2bf(p[t]); o[t + 4] = f2bf(q[t]); }
    *(u16x8*)(dst + (size_t)g * 8) = o;
  }
}

// ---------------------------------------------------------------------------
// Pre-pass B: dequantize int4 -> Wt bf16 bits, [128][64] tiles, UNSWIZZLED
// (register-destined in GEMM: banks irrelevant, coalescing matters).
// ---------------------------------------------------------------------------
__global__ __launch_bounds__(256) void dequant_tiled(
    const uint32_t* __restrict__ qweight, const uint32_t* __restrict__ qzeros,
    const float* __restrict__ scales, u16* __restrict__ wt) {
  const int kt = blockIdx.x, nt = blockIdx.y;
  const int n0 = nt * 128;
  const int gq = kt >> 1;                       // quant group = kt*64/128
  u16* dst = wt + ((size_t)(nt * KT64 + kt)) * 8192;
#pragma unroll
  for (int i = 0; i < 4; ++i) {
    const int g  = i * 256 + threadIdx.x;
    const int nl = g >> 3;
    const int cg = g & 7;                       // no swizzle
    const int n  = n0 + nl;
    const uint32_t zq = qzeros[(size_t)gq * (N_DIM / 8) + (n >> 3)];
    const int   z   = (int)((zq >> ((n & 7) * 4)) & 15u);
    const float s   = scales[(size_t)gq * N_DIM + n];
    const float nzs = -s * (float)z;            // w = fma(q,s,-z*s): exact in f32
    const uint32_t q = qweight[(size_t)(kt * 8 + cg) * N_DIM + n];
    u16x8 o;
#pragma unroll
    for (int t = 0; t < 8; ++t) {
      const int qv = (int)((q >> (t * 4)) & 15u);
      o[t] = f2bf(fmaf((float)qv, s, nzs));
    }
    *(u16x8*)(dst + (size_t)g * 8) = o;
  }
}

// ---------------------------------------------------------------------------
// GEMM: 256x256 tile, BK=64, 8 waves (2M x 4N), per-wave 128x64 (8x4 frags).
// ---------------------------------------------------------------------------
#define LDF(p)  __builtin_bit_cast(bfv8, *(const u16x8*)(p))
#define BAR()   asm volatile("s_barrier" ::: "memory")
#define VMW_(n) asm volatile("s_waitcnt vmcnt(" #n ")" ::: "memory")
#define VMW(n)  VMW_(n)

// stage half-tile h of A K-tile ktt into ring buffer (ktt & 3)
#define STAGE_AH(ktt, h) do {                                                 \
    const u16* s_ = at0 + ((size_t)(h) * KT64 + (ktt)) * 8192;                \
    u16* d_ = &As[(((ktt) & 3) * 16384) + (h) * 8192 + wave * 512];           \
    async_load16(s_ + (size_t)tid * 8, d_);                                   \
    async_load16(s_ + (size_t)(512 + tid) * 8, d_ + 4096);                    \
  } while (0)

// read A fragment pair {ib, ib+1} x {ks0, ks1} from ring buffer sbx
#define RD_AP(v, ib, sbx) do {                                                \
    v[0] = LDF(&As[(sbx) * 16384 + aoff + (ib) * 1024 + kq0]);                \
    v[1] = LDF(&As[(sbx) * 16384 + aoff + (ib) * 1024 + kq1]);                \
    v[2] = LDF(&As[(sbx) * 16384 + aoff + ((ib) + 1) * 1024 + kq0]);          \
    v[3] = LDF(&As[(sbx) * 16384 + aoff + ((ib) + 1) * 1024 + kq1]);          \
  } while (0)

// load B fragments j = jb, jb+1 (both ks) of K-tile ktt straight to regs
#define BLOAD4(dst, ktt, jb) do {                                             \
    const u16* p_ = gB + (size_t)(ktt) * 8192 + (jb) * 1024;                  \
    dst[2 * (jb)]     = LDF(p_);        dst[2 * (jb) + 1] = LDF(p_ + 32);     \
    dst[2 * (jb) + 2] = LDF(p_ + 1024); dst[2 * (jb) + 3] = LDF(p_ + 1056);   \
  } while (0)

// 16 MFMA for i-pair {ib, ib+1}: all j, both ks
#define MM(ib, av, bv) do {                                                   \
    __builtin_amdgcn_s_setprio(1);                                            \
    _Pragma("unroll")                                                         \
    for (int ks_ = 0; ks_ < 2; ++ks_)                                         \
      _Pragma("unroll")                                                       \
      for (int ii_ = 0; ii_ < 2; ++ii_)                                       \
        _Pragma("unroll")                                                     \
        for (int j_ = 0; j_ < 4; ++j_)                                        \
          acc[(ib) + ii_][j_] = __builtin_amdgcn_mfma_f32_16x16x32_bf16(      \
              av[2 * ii_ + ks_], bv[2 * j_ + ks_], acc[(ib) + ii_][j_],       \
              0, 0, 0);                                                       \
    __builtin_amdgcn_s_setprio(0);                                            \
  } while (0)

// One K-tile. DO_B / DO_ST are 0/1 literals, NVM is the vmcnt literal.
// P0: rdA23 | loadB(kt+1) j01 | MM0      (no barrier)
// P1: rdA45 | loadB(kt+1) j23 | MM2      (no barrier)
// P2: rdA67 | MM4 | BAR  (producer-WAR: buf (kt-1)&3 free after this)
// P3: rdA01(kt+1) | stage A(kt+3) | MM6 | VMW | BAR (consumer-RAW)
#define KTILE(kt, bcur, bnxt, DO_B, DO_ST, NVM) do {                          \
    const int sb_  = (kt) & 3;                                                \
    RD_AP(a23, 2, sb_);                                                       \
    if (DO_B) { BLOAD4(bnxt, (kt) + 1, 0); }                                  \
    MM(0, a01, bcur);                                                         \
    RD_AP(a45, 4, sb_);                                                       \
    if (DO_B) { BLOAD4(bnxt, (kt) + 1, 2); }                                  \
    MM(2, a23, bcur);                                                         \
    RD_AP(a67, 6, sb_);                                                       \
    MM(4, a45, bcur);                                                         \
    BAR();                                                                    \
    if (DO_B) { RD_AP(a01, 0, ((kt) + 1) & 3); }                              \
    if (DO_ST) { STAGE_AH((kt) + 3, 0); STAGE_AH((kt) + 3, 1); }              \
    MM(6, a67, bcur);                                                         \
    VMW(NVM);                                                                 \
    BAR();                                                                    \
  } while (0)

__global__ __launch_bounds__(512, 2) void gemm_256(
    const u16* __restrict__ xb, const u16* __restrict__ wt,
    const float* __restrict__ bias, float* __restrict__ out) {
  __shared__ __align__(16) u16 As[4 * 16384];   // 4-deep A ring, 32KB each

  const int tid  = threadIdx.x;
  const int lane = tid & 63;
  const int wave = tid >> 6;
  const int wm   = wave >> 2;        // 0..1  (M)
  const int wn   = wave & 3;         // 0..3  (N)
  const int lrow = lane & 15;
  const int lk   = lane >> 4;        // k-quad 0..3
  const int swz  = lrow & 7;

  // XCD-aware bijective block swizzle (valid when nwg % 8 == 0)
  const int nwg = gridDim.x * gridDim.y;
  int wg = blockIdx.y * gridDim.x + blockIdx.x;
  if ((nwg & 7) == 0) wg = (wg & 7) * (nwg >> 3) + (wg >> 3);
  const int bx = wg % gridDim.x;
  const int by = wg / gridDim.x;
  const int n0 = bx * 256;
  const int m0 = by * 256;

  const u16* at0 = xb + (size_t)(2 * by) * KT64 * 8192;

  // per-lane global base for B fragments (unswizzled workspace)
  const u16* gB = wt + ((size_t)(2 * bx + (wn >> 1)) * KT64) * 8192
                + ((wn & 1) * 64 + lrow) * 64 + lk * 8;

  const int aoff = wm * 8192 + lrow * 64;      // A-side: swizzled reads
  const int kq0  = (lk ^ swz) * 8;
  const int kq1  = ((4 + lk) ^ swz) * 8;

  bfv8 a01[4], a23[4], a45[4], a67[4], bA[8], bB[8];
  f32x4 acc[8][4];
#pragma unroll
  for (int i = 0; i < 8; ++i)
#pragma unroll
    for (int j = 0; j < 4; ++j) acc[i][j] = f32x4{0.f, 0.f, 0.f, 0.f};

  // prologue: B(0) loads first (oldest), then stage A(0..2).
  // VMW(4) completes B(0), A(0), A(1); leaves A(2) staging in flight —
  // same invariant as steady state (VMW at tile T leaves only stage(T+3)).
  BLOAD4(bA, 0, 0); BLOAD4(bA, 0, 2);
  STAGE_AH(0, 0); STAGE_AH(0, 1);
  STAGE_AH(1, 0); STAGE_AH(1, 1);
  STAGE_AH(2, 0); STAGE_AH(2, 1);
  VMW(4); BAR();
  RD_AP(a01, 0, 0);                  // lookahead read, "P3 of kt=-1"

#pragma unroll 1
  for (int kt2 = 0; kt2 < 30; ++kt2) {   // kt = 0..59: full steady state
    const int kt = 2 * kt2;
    KTILE(kt,     bA, bB, 1, 1, 4);
    KTILE(kt + 1, bB, bA, 1, 1, 4);
  }
  // tail: kt = 60..63
  KTILE(60, bA, bB, 1, 1, 4);   // stages A(63)
  KTILE(61, bB, bA, 1, 0, 0);   // drain: A(63) + B(62) loads
  KTILE(62, bA, bB, 1, 0, 0);   // drain: B(63) loads
  KTILE(63, bB, bA, 0, 0, 0);   // pure compute

  // epilogue: ref rounding f16(f16(acc) + bias); store f32.
  // C/D layout (m89): col = lane&15, row = (lane>>4)*4 + reg
#pragma unroll
  for (int j = 0; j < 4; ++j) {
    const int n = n0 + wn * 64 + j * 16 + lrow;
    const float bvf = bias[n];
#pragma unroll
    for (int i = 0; i < 8; ++i) {
      const int mrow = m0 + wm * 128 + i * 16 + lk * 4;
#pragma unroll
      for (int r = 0; r < 4; ++r) {
        out[(size_t)(mrow + r) * N_DIM + n] = f16r(f16r(acc[i][j][r]) + bvf);
      }
    }
  }
}

// ---------------------------------------------------------------------------
// Fused fallback (no workspace / odd M): R4 structure, register staging.
// ---------------------------------------------------------------------------
__global__ __launch_bounds__(256) void gemm_fused(
    const float* __restrict__ xf, const uint32_t* __restrict__ qw,
    const uint32_t* __restrict__ qzeros, const float* __restrict__ scales,
    const float* __restrict__ bias, float* __restrict__ out) {
  __shared__ __align__(16) u16 As[128 * LSTR];
  __shared__ __align__(16) u16 Bs[128 * LSTR];

  const int tid  = threadIdx.x;
  const int lane = tid & 63;
  const int wave = tid >> 6;
  const int n0 = blockIdx.x * 128;
  const int m0 = blockIdx.y * 128;
  const int m_off = (wave >> 1) * 64;
  const int n_off = (wave & 1) * 64;
  const int lrow  = lane & 15;
  const int lk    = lane >> 4;
  const int sm = tid >> 3;
  const int sc = tid & 7;

  f32x4 acc[4][4];
#pragma unroll
  for (int i = 0; i < 4; ++i)
#pragma unroll
    for (int j = 0; j < 4; ++j) acc[i][j] = f32x4{0.f, 0.f, 0.f, 0.f};

  const int ncol = n0 + (tid & 127);
  float s_cur = 0.f, nzs_cur = 0.f;

  for (int kt = 0; kt < K_DIM / 64; ++kt) {
    const int k0 = kt * 64;
    u16x8 av[4];
#pragma unroll
    for (int i = 0; i < 4; ++i) {
      const int m = i * 32 + sm;
      const float* sp = xf + (size_t)(m0 + m) * K_DIM + (k0 + sc * 8);
      const f32x4 p = *(const f32x4*)sp;
      const f32x4 q4 = *(const f32x4*)(sp + 4);
#pragma unroll
      for (int t = 0; t < 4; ++t) { av[i][t] = f2bf(p[t]); av[i][t+4] = f2bf(q4[t]); }
    }
    u16x8 bv[4];
    if ((k0 & (GS - 1)) == 0) {
      const int g = k0 >> 7;
      const uint32_t zq = qzeros[(size_t)g * (N_DIM / 8) + (ncol >> 3)];
      const int z = (int)((zq >> ((ncol & 7) * 4)) & 15u);
      s_cur = scales[(size_t)g * N_DIM + ncol];
      nzs_cur = -s_cur * (float)z;
    }
#pragma unroll
    for (int i = 0; i < 4; ++i) {
      const int k8l = (tid >> 7) + i * 2;
      const uint32_t q = qw[(size_t)(k0 / 8 + k8l) * N_DIM + ncol];
#pragma unroll
      for (int t = 0; t < 8; ++t) {
        const int qv = (int)((q >> (t * 4)) & 15u);
        bv[i][t] = f2bf(fmaf((float)qv, s_cur, nzs_cur));
      }
    }
#pragma unroll
    for (int i = 0; i < 4; ++i)
      *(u16x8*)&As[(i * 32 + sm) * LSTR + sc * 8] = av[i];
    {
      const int nl = tid & 127;
#pragma unroll
      for (int i = 0; i < 4; ++i) {
        const int k8l = (tid >> 7) + i * 2;
        *(u16x8*)&Bs[nl * LSTR + k8l * 8] = bv[i];
      }
    }
    __syncthreads();
#pragma unroll
    for (int ks = 0; ks < 2; ++ks) {
      const int c = (ks * 4 + lk) * 8;
      bfv8 a[4], b[4];
#pragma unroll
      for (int i = 0; i < 4; ++i)
        a[i] = __builtin_bit_cast(bfv8,
                 *(const u16x8*)&As[(m_off + i * 16 + lrow) * LSTR + c]);
#pragma unroll
      for (int j = 0; j < 4; ++j)
        b[j] = __builtin_bit_cast(bfv8,
                 *(const u16x8*)&Bs[(n_off + j * 16 + lrow) * LSTR + c]);
#pragma unroll
      for (int i = 0; i < 4; ++i)
#pragma unroll
        for (int j = 0; j < 4; ++j)
          acc[i][j] = __builtin_amdgcn_mfma_f32_16x16x32_bf16(a[i], b[j],
                                                              acc[i][j], 0, 0, 0);
    }
    __syncthreads();
  }
#pragma unroll
  for (int j = 0; j < 4; ++j) {
    const int n = n0 + n_off + j * 16 + lrow;
    const float bvf = bias[n];
#pragma unroll
    for (int i = 0; i < 4; ++i) {
      const int mrow = m0 + m_off + i * 16 + lk * 4;
#pragma unroll
      for (int r = 0; r < 4; ++r)
        out[(size_t)(mrow + r) * N_DIM + n] = f16r(f16r(acc[i][j][r]) + bvf);
    }
  }
}

extern "C" void kernel_launch(void* const* d_in, const int* in_sizes, int n_in,
                              void* d_out, int out_size, void* d_ws, size_t ws_size,
                              hipStream_t stream) {
  // Identify inputs by element count (all five distinct).
  const float* x = nullptr;      const uint32_t* qweight = nullptr;
  const uint32_t* qzeros = nullptr;
  const float* scales = nullptr; const float* bias = nullptr;
  int M = 4096;
  for (int i = 0; i < n_in; ++i) {
    const long long s = in_sizes[i];
    if      (s == (long long)(K_DIM / 8) * N_DIM) qweight = (const uint32_t*)d_in[i];
    else if (s == (long long)(K_DIM / GS) * (N_DIM / 8)) qzeros = (const uint32_t*)d_in[i];
    else if (s == (long long)(K_DIM / GS) * N_DIM) scales = (const float*)d_in[i];
    else if (s == (long long)N_DIM) bias = (const float*)d_in[i];
    else { x = (const float*)d_in[i]; M = (int)(s / K_DIM); }
  }
  float* out = (float*)d_out;

  const size_t xb_bytes = (size_t)M * K_DIM * sizeof(u16);      // 33.5 MB
  const size_t wt_bytes = (size_t)N_DIM * K_DIM * sizeof(u16);  // 90.2 MB

  if (ws_size >= xb_bytes + wt_bytes && (M % 256) == 0) {
    u16* xbp = (u16*)d_ws;
    u16* wtp = (u16*)((char*)d_ws + xb_bytes);
    convert_x_tiled<<<dim3(KT64, M / 128), 256, 0, stream>>>(x, xbp);
    dequant_tiled<<<dim3(KT64, N_DIM / 128), 256, 0, stream>>>(
        qweight, qzeros, scales, wtp);
    gemm_256<<<dim3(N_DIM / 256, M / 256), 512, 0, stream>>>(
        xbp, wtp, bias, out);
  } else {
    gemm_fused<<<dim3(N_DIM / 128, (M + 127) / 128), 256, 0, stream>>>(
        x, qweight, qzeros, scales, bias, out);
  }
}

// Round 4
// 620.212 us; speedup vs baseline: 1.1301x; 1.1301x over previous
//
#include <hip/hip_runtime.h>
#include <cstdint>
#include <cstddef>

// ExllamaLinear: out[M,N] = f16( f16( x[M,K] @ ((q - z) * s)[K,N] ) + bias )
// M = 4096, K = 4096, N = 11008, group 128 along K. fp16 tensors stored f32.
//
// R9: R7 structure (both operands through LDS, 2-buffer, BK=64, 4 phases,
// lookahead register pipelining, counted vmcnt(2)/tile) + the missing piece:
// __builtin_amdgcn_sched_barrier(0) between each phase's {ds_reads, stage}
// and its MFMA cluster. Per-wave issue is in-order, so compile-order pinning
// guarantees reads enter the LDS queue BEFORE the MFMA cluster and complete
// under it (R7's 40% MfmaUtil = compiler sinking reads to their use,
// serializing the LDS and MFMA pipes; m201's 62% comes from pinned reads).
// Stage schedule (steady tile kt, buf c=kt&1):
//   P0: rd a23(c)   | stage A(kt+1)h0 | SBAR | MM(i01) | BAR
//   P1: rd a45(c)   | stage A(kt+1)h1 | SBAR | MM(i23) | BAR
//   P2: rd a67(c)   | stage B(kt+2)h0 | SBAR | MM(i45) | VMW(2) | BAR
//   P3: rd B(kt+1)+a01(c^1) | stage B(kt+2)h1 | SBAR | MM(i67) | BAR
// VMW(2) at P2-end completes B(kt+1)+A(kt+1) (cover >= 1 phase), leaves
// B(kt+2)h0 in flight — counted, never 0 in steady state.

typedef unsigned short u16;
typedef u16    u16x8  __attribute__((ext_vector_type(8)));
typedef __bf16 bfv8   __attribute__((ext_vector_type(8)));
typedef float  f32x4  __attribute__((ext_vector_type(4)));

#define K_DIM 4096
#define N_DIM 11008
#define GS    128
#define KT64  (K_DIM / 64)   // 64 k-tiles of 64
#define LSTR  72             // fused-fallback padded LDS stride

__device__ __forceinline__ u16 f2bf(float f) {  // RTNE f32 -> bf16 bits
  union { float f; uint32_t u; } v;
  v.f = f;
  uint32_t u = v.u + 0x7FFFu + ((v.u >> 16) & 1u);
  return (u16)(u >> 16);
}
__device__ __forceinline__ float f16r(float v) {  // fp16 round-trip (RTNE)
  return (float)(_Float16)v;
}
__device__ __forceinline__ void async_load16(const u16* g, u16* l) {
  __builtin_amdgcn_global_load_lds(
      (const __attribute__((address_space(1))) uint32_t*)g,
      (__attribute__((address_space(3))) uint32_t*)l, 16, 0, 0);
}

// ---------------------------------------------------------------------------
// Pre-pass A: x f32 -> bf16 bits, [128][64] tiles, XOR-swizzled granules.
// granule g: row nl=g>>3, k-granule cg=(g&7)^(nl&7). Sequential 16B writes.
// ---------------------------------------------------------------------------
__global__ __launch_bounds__(256) void convert_x_tiled(
    const float* __restrict__ x, u16* __restrict__ xb) {
  const int kt = blockIdx.x, mt = blockIdx.y;
  const int k0 = kt * 64, m0 = mt * 128;
  u16* dst = xb + ((size_t)(mt * KT64 + kt)) * 8192;
#pragma unroll
  for (int i = 0; i < 4; ++i) {
    const int g  = i * 256 + threadIdx.x;
    const int nl = g >> 3;
    const int cg = (g & 7) ^ (nl & 7);
    const float* sp = x + (size_t)(m0 + nl) * K_DIM + (k0 + cg * 8);
    const f32x4 p = *(const f32x4*)sp;
    const f32x4 q = *(const f32x4*)(sp + 4);
    u16x8 o;
#pragma unroll
    for (int t = 0; t < 4; ++t) { o[t] = f2bf(p[t]); o[t + 4] = f2bf(q[t]); }
    *(u16x8*)(dst + (size_t)g * 8) = o;
  }
}

// ---------------------------------------------------------------------------
// Pre-pass B: dequantize int4 -> Wt bf16 bits, [128][64] tiles, SAME XOR
// swizzle (B goes through LDS again). One granule = one qweight int32.
// ---------------------------------------------------------------------------
__global__ __launch_bounds__(256) void dequant_tiled(
    const uint32_t* __restrict__ qweight, const uint32_t* __restrict__ qzeros,
    const float* __restrict__ scales, u16* __restrict__ wt) {
  const int kt = blockIdx.x, nt = blockIdx.y;
  const int n0 = nt * 128;
  const int gq = kt >> 1;                       // quant group = kt*64/128
  u16* dst = wt + ((size_t)(nt * KT64 + kt)) * 8192;
#pragma unroll
  for (int i = 0; i < 4; ++i) {
    const int g  = i * 256 + threadIdx.x;
    const int nl = g >> 3;
    const int cg = (g & 7) ^ (nl & 7);
    const int n  = n0 + nl;
    const uint32_t zq = qzeros[(size_t)gq * (N_DIM / 8) + (n >> 3)];
    const int   z   = (int)((zq >> ((n & 7) * 4)) & 15u);
    const float s   = scales[(size_t)gq * N_DIM + n];
    const float nzs = -s * (float)z;            // w = fma(q,s,-z*s): exact in f32
    const uint32_t q = qweight[(size_t)(kt * 8 + cg) * N_DIM + n];
    u16x8 o;
#pragma unroll
    for (int t = 0; t < 8; ++t) {
      const int qv = (int)((q >> (t * 4)) & 15u);
      o[t] = f2bf(fmaf((float)qv, s, nzs));
    }
    *(u16x8*)(dst + (size_t)g * 8) = o;
  }
}

// ---------------------------------------------------------------------------
// GEMM: 256x256 tile, BK=64, 8 waves (2M x 4N), per-wave 128x64 (8x4 frags).
// ---------------------------------------------------------------------------
#define LDF(p)  __builtin_bit_cast(bfv8, *(const u16x8*)(p))
#define BAR()   asm volatile("s_barrier" ::: "memory")
#define VMW_(n) asm volatile("s_waitcnt vmcnt(" #n ")" ::: "memory")
#define VMW(n)  VMW_(n)
#define SBAR()  __builtin_amdgcn_sched_barrier(0)

// stage half-tile h of A/B K-tile ktt into buffer (ktt & 1)
#define STAGE_AH(ktt, h) do {                                                 \
    const u16* s_ = at0 + ((size_t)(h) * KT64 + (ktt)) * 8192;                \
    u16* d_ = &As[(((ktt) & 1) * 16384) + (h) * 8192 + wave * 512];           \
    async_load16(s_ + (size_t)tid * 8, d_);                                   \
    async_load16(s_ + (size_t)(512 + tid) * 8, d_ + 4096);                    \
  } while (0)
#define STAGE_BH(ktt, h) do {                                                 \
    const u16* s_ = bt0 + ((size_t)(h) * KT64 + (ktt)) * 8192;                \
    u16* d_ = &Bs[(((ktt) & 1) * 16384) + (h) * 8192 + wave * 512];           \
    async_load16(s_ + (size_t)tid * 8, d_);                                   \
    async_load16(s_ + (size_t)(512 + tid) * 8, d_ + 4096);                    \
  } while (0)

// read A fragment pair {ib, ib+1} x {ks0, ks1} from buffer sbx
#define RD_AP(v, ib, sbx) do {                                                \
    v[0] = LDF(&As[(sbx) * 16384 + aoff + (ib) * 1024 + kq0]);                \
    v[1] = LDF(&As[(sbx) * 16384 + aoff + (ib) * 1024 + kq1]);                \
    v[2] = LDF(&As[(sbx) * 16384 + aoff + ((ib) + 1) * 1024 + kq0]);          \
    v[3] = LDF(&As[(sbx) * 16384 + aoff + ((ib) + 1) * 1024 + kq1]);          \
  } while (0)
// read all 8 B fragments (j 0..3 x ks 0..1) from buffer sbx
#define RD_B8(v, sbx) do {                                                    \
    _Pragma("unroll")                                                         \
    for (int j_ = 0; j_ < 4; ++j_) {                                          \
      v[2 * j_]     = LDF(&Bs[(sbx) * 16384 + boff + j_ * 1024 + kq0]);       \
      v[2 * j_ + 1] = LDF(&Bs[(sbx) * 16384 + boff + j_ * 1024 + kq1]);       \
    }                                                                         \
  } while (0)

// 16 MFMA for i-pair {ib, ib+1}: all j, both ks (dependent pairs 8 apart)
#define MM(ib, av, bv) do {                                                   \
    __builtin_amdgcn_s_setprio(1);                                            \
    _Pragma("unroll")                                                         \
    for (int ks_ = 0; ks_ < 2; ++ks_)                                         \
      _Pragma("unroll")                                                       \
      for (int ii_ = 0; ii_ < 2; ++ii_)                                       \
        _Pragma("unroll")                                                     \
        for (int j_ = 0; j_ < 4; ++j_)                                        \
          acc[(ib) + ii_][j_] = __builtin_amdgcn_mfma_f32_16x16x32_bf16(      \
              av[2 * ii_ + ks_], bv[2 * j_ + ks_], acc[(ib) + ii_][j_],       \
              0, 0, 0);                                                       \
    __builtin_amdgcn_s_setprio(0);                                            \
  } while (0)

// One K-tile, 4 phases. VMWSTMT is the P2-end wait statement.
#define KTILE(kt, bcur, bnxt, DO_STA, DO_STB, DO_NEXT, VMWSTMT) do {          \
    const int sb_ = (kt) & 1;                                                 \
    /* P0 */                                                                  \
    RD_AP(a23, 2, sb_);                                                       \
    if (DO_STA) { STAGE_AH((kt) + 1, 0); }                                    \
    SBAR();                                                                   \
    MM(0, a01, bcur);                                                         \
    BAR();                                                                    \
    /* P1 */                                                                  \
    RD_AP(a45, 4, sb_);                                                       \
    if (DO_STA) { STAGE_AH((kt) + 1, 1); }                                    \
    SBAR();                                                                   \
    MM(2, a23, bcur);                                                         \
    BAR();                                                                    \
    /* P2 */                                                                  \
    RD_AP(a67, 6, sb_);                                                       \
    if (DO_STB) { STAGE_BH((kt) + 2, 0); }                                    \
    SBAR();                                                                   \
    MM(4, a45, bcur);                                                         \
    VMWSTMT;                                                                  \
    BAR();                                                                    \
    /* P3 */                                                                  \
    if (DO_NEXT) { RD_B8(bnxt, sb_ ^ 1); RD_AP(a01, 0, sb_ ^ 1); }            \
    if (DO_STB) { STAGE_BH((kt) + 2, 1); }                                    \
    SBAR();                                                                   \
    MM(6, a67, bcur);                                                         \
    BAR();                                                                    \
  } while (0)

__global__ __launch_bounds__(512, 2) void gemm_256(
    const u16* __restrict__ xb, const u16* __restrict__ wt,
    const float* __restrict__ bias, float* __restrict__ out) {
  __shared__ __align__(16) u16 As[2 * 16384];   // 2 bufs x 2 halves x 8192
  __shared__ __align__(16) u16 Bs[2 * 16384];

  const int tid  = threadIdx.x;
  const int lane = tid & 63;
  const int wave = tid >> 6;
  const int wm   = wave >> 2;        // 0..1  (M)
  const int wn   = wave & 3;         // 0..3  (N)
  const int lrow = lane & 15;
  const int lk   = lane >> 4;        // k-quad 0..3
  const int swz  = lrow & 7;

  // XCD-aware bijective block swizzle (valid when nwg % 8 == 0)
  const int nwg = gridDim.x * gridDim.y;
  int wg = blockIdx.y * gridDim.x + blockIdx.x;
  if ((nwg & 7) == 0) wg = (wg & 7) * (nwg >> 3) + (wg >> 3);
  const int bx = wg % gridDim.x;
  const int by = wg / gridDim.x;
  const int n0 = bx * 256;
  const int m0 = by * 256;

  const u16* at0 = xb + (size_t)(2 * by) * KT64 * 8192;
  const u16* bt0 = wt + (size_t)(2 * bx) * KT64 * 8192;

  const int aoff = wm * 8192 + lrow * 64;
  const int boff = (wn >> 1) * 8192 + ((wn & 1) * 64 + lrow) * 64;
  const int kq0  = (lk ^ swz) * 8;
  const int kq1  = ((4 + lk) ^ swz) * 8;

  bfv8 a01[4], a23[4], a45[4], a67[4], bA[8], bB[8];
  f32x4 acc[8][4];
#pragma unroll
  for (int i = 0; i < 8; ++i)
#pragma unroll
    for (int j = 0; j < 4; ++j) acc[i][j] = f32x4{0.f, 0.f, 0.f, 0.f};

  // prologue: stage B(0), A(0), B(1), A(1) (16 loads). VMW(8) completes
  // B(0)+A(0), leaves B(1)+A(1) in flight — matches steady invariant
  // (tile 0's VMW(2) then completes B(1)+A(1), leaving B(2)h0).
  STAGE_BH(0, 0); STAGE_BH(0, 1); STAGE_AH(0, 0); STAGE_AH(0, 1);
  STAGE_BH(1, 0); STAGE_BH(1, 1); STAGE_AH(1, 0); STAGE_AH(1, 1);
  VMW(8); BAR();
  RD_B8(bA, 0); RD_AP(a01, 0, 0);    // lookahead reads for tile 0 P0

  // tile 0: A(1) already staged in prologue (DO_STA=0); stages B(2)
  KTILE(0, bA, bB, 0, 1, 1, VMW(2));

#pragma unroll 1
  for (int kt2 = 0; kt2 < 30; ++kt2) {   // tiles 1..60, steady state
    const int kt = 2 * kt2 + 1;
    KTILE(kt,     bB, bA, 1, 1, 1, VMW(2));
    KTILE(kt + 1, bA, bB, 1, 1, 1, VMW(2));
  }
  // tile 61 (bB): stages A(62), B(63); steady VMW(2)
  KTILE(61, bB, bA, 1, 1, 1, VMW(2));
  // tile 62 (bA): stages A(63) only; drain all at P2-end (1-phase cover)
  KTILE(62, bA, bB, 1, 0, 1, VMW(0));
  // tile 63 (bB): pure compute
  KTILE(63, bB, bA, 0, 0, 0, (void)0);

  // epilogue: ref rounding f16(f16(acc) + bias); store f32.
  // C/D layout (m89): col = lane&15, row = (lane>>4)*4 + reg
#pragma unroll
  for (int j = 0; j < 4; ++j) {
    const int n = n0 + wn * 64 + j * 16 + lrow;
    const float bvf = bias[n];
#pragma unroll
    for (int i = 0; i < 8; ++i) {
      const int mrow = m0 + wm * 128 + i * 16 + lk * 4;
#pragma unroll
      for (int r = 0; r < 4; ++r) {
        out[(size_t)(mrow + r) * N_DIM + n] = f16r(f16r(acc[i][j][r]) + bvf);
      }
    }
  }
}

// ---------------------------------------------------------------------------
// Fused fallback (no workspace / odd M): R4 structure, register staging.
// ---------------------------------------------------------------------------
__global__ __launch_bounds__(256) void gemm_fused(
    const float* __restrict__ xf, const uint32_t* __restrict__ qw,
    const uint32_t* __restrict__ qzeros, const float* __restrict__ scales,
    const float* __restrict__ bias, float* __restrict__ out) {
  __shared__ __align__(16) u16 As[128 * LSTR];
  __shared__ __align__(16) u16 Bs[128 * LSTR];

  const int tid  = threadIdx.x;
  const int lane = tid & 63;
  const int wave = tid >> 6;
  const int n0 = blockIdx.x * 128;
  const int m0 = blockIdx.y * 128;
  const int m_off = (wave >> 1) * 64;
  const int n_off = (wave & 1) * 64;
  const int lrow  = lane & 15;
  const int lk    = lane >> 4;
  const int sm = tid >> 3;
  const int sc = tid & 7;

  f32x4 acc[4][4];
#pragma unroll
  for (int i = 0; i < 4; ++i)
#pragma unroll
    for (int j = 0; j < 4; ++j) acc[i][j] = f32x4{0.f, 0.f, 0.f, 0.f};

  const int ncol = n0 + (tid & 127);
  float s_cur = 0.f, nzs_cur = 0.f;

  for (int kt = 0; kt < K_DIM / 64; ++kt) {
    const int k0 = kt * 64;
    u16x8 av[4];
#pragma unroll
    for (int i = 0; i < 4; ++i) {
      const int m = i * 32 + sm;
      const float* sp = xf + (size_t)(m0 + m) * K_DIM + (k0 + sc * 8);
      const f32x4 p = *(const f32x4*)sp;
      const f32x4 q4 = *(const f32x4*)(sp + 4);
#pragma unroll
      for (int t = 0; t < 4; ++t) { av[i][t] = f2bf(p[t]); av[i][t+4] = f2bf(q4[t]); }
    }
    u16x8 bv[4];
    if ((k0 & (GS - 1)) == 0) {
      const int g = k0 >> 7;
      const uint32_t zq = qzeros[(size_t)g * (N_DIM / 8) + (ncol >> 3)];
      const int z = (int)((zq >> ((ncol & 7) * 4)) & 15u);
      s_cur = scales[(size_t)g * N_DIM + ncol];
      nzs_cur = -s_cur * (float)z;
    }
#pragma unroll
    for (int i = 0; i < 4; ++i) {
      const int k8l = (tid >> 7) + i * 2;
      const uint32_t q = qw[(size_t)(k0 / 8 + k8l) * N_DIM + ncol];
#pragma unroll
      for (int t = 0; t < 8; ++t) {
        const int qv = (int)((q >> (t * 4)) & 15u);
        bv[i][t] = f2bf(fmaf((float)qv, s_cur, nzs_cur));
      }
    }
#pragma unroll
    for (int i = 0; i < 4; ++i)
      *(u16x8*)&As[(i * 32 + sm) * LSTR + sc * 8] = av[i];
    {
      const int nl = tid & 127;
#pragma unroll
      for (int i = 0; i < 4; ++i) {
        const int k8l = (tid >> 7) + i * 2;
        *(u16x8*)&Bs[nl * LSTR + k8l * 8] = bv[i];
      }
    }
    __syncthreads();
#pragma unroll
    for (int ks = 0; ks < 2; ++ks) {
      const int c = (ks * 4 + lk) * 8;
      bfv8 a[4], b[4];
#pragma unroll
      for (int i = 0; i < 4; ++i)
        a[i] = __builtin_bit_cast(bfv8,
                 *(const u16x8*)&As[(m_off + i * 16 + lrow) * LSTR + c]);
#pragma unroll
      for (int j = 0; j < 4; ++j)
        b[j] = __builtin_bit_cast(bfv8,
                 *(const u16x8*)&Bs[(n_off + j * 16 + lrow) * LSTR + c]);
#pragma unroll
      for (int i = 0; i < 4; ++i)
#pragma unroll
        for (int j = 0; j < 4; ++j)
          acc[i][j] = __builtin_amdgcn_mfma_f32_16x16x32_bf16(a[i], b[j],
                                                              acc[i][j], 0, 0, 0);
    }
    __syncthreads();
  }
#pragma unroll
  for (int j = 0; j < 4; ++j) {
    const int n = n0 + n_off + j * 16 + lrow;
    const float bvf = bias[n];
#pragma unroll
    for (int i = 0; i < 4; ++i) {
      const int mrow = m0 + m_off + i * 16 + lk * 4;
#pragma unroll
      for (int r = 0; r < 4; ++r)
        out[(size_t)(mrow + r) * N_DIM + n] = f16r(f16r(acc[i][j][r]) + bvf);
    }
  }
}

extern "C" void kernel_launch(void* const* d_in, const int* in_sizes, int n_in,
                              void* d_out, int out_size, void* d_ws, size_t ws_size,
                              hipStream_t stream) {
  // Identify inputs by element count (all five distinct).
  const float* x = nullptr;      const uint32_t* qweight = nullptr;
  const uint32_t* qzeros = nullptr;
  const float* scales = nullptr; const float* bias = nullptr;
  int M = 4096;
  for (int i = 0; i < n_in; ++i) {
    const long long s = in_sizes[i];
    if      (s == (long long)(K_DIM / 8) * N_DIM) qweight = (const uint32_t*)d_in[i];
    else if (s == (long long)(K_DIM / GS) * (N_DIM / 8)) qzeros = (const uint32_t*)d_in[i];
    else if (s == (long long)(K_DIM / GS) * N_DIM) scales = (const float*)d_in[i];
    else if (s == (long long)N_DIM) bias = (const float*)d_in[i];
    else { x = (const float*)d_in[i]; M = (int)(s / K_DIM); }
  }
  float* out = (float*)d_out;

  const size_t xb_bytes = (size_t)M * K_DIM * sizeof(u16);      // 33.5 MB
  const size_t wt_bytes = (size_t)N_DIM * K_DIM * sizeof(u16);  // 90.2 MB

  if (ws_size >= xb_bytes + wt_bytes && (M % 256) == 0) {
    u16* xbp = (u16*)d_ws;
    u16* wtp = (u16*)((char*)d_ws + xb_bytes);
    convert_x_tiled<<<dim3(KT64, M / 128), 256, 0, stream>>>(x, xbp);
    dequant_tiled<<<dim3(KT64, N_DIM / 128), 256, 0, stream>>>(
        qweight, qzeros, scales, wtp);
    gemm_256<<<dim3(N_DIM / 256, M / 256), 512, 0, stream>>>(
        xbp, wtp, bias, out);
  } else {
    gemm_fused<<<dim3(N_DIM / 128, (M + 127) / 128), 256, 0, stream>>>(
        x, qweight, qzeros, scales, bias, out);
  }
}

// Round 5
// 604.702 us; speedup vs baseline: 1.1591x; 1.0256x over previous
//
#include <hip/hip_runtime.h>
#include <cstdint>
#include <cstddef>

// ExllamaLinear: out[M,N] = f16( f16( x[M,K] @ ((q - z) * s)[K,N] ) + bias )
// M = 4096, K = 4096, N = 11008, group 128 along K. fp16 tensors stored f32.
//
// R10: R9 structure unchanged EXCEPT barrier/waitcnt mechanics.
// R6-R9 used asm volatile(... ::: "memory") for s_barrier / s_waitcnt; the
// "memory" clobber makes the inline asm may-load/may-store, so the backend
// conservatively drains vmcnt(0) lgkmcnt(0) before EVERY barrier — i.e. all
// three schedules silently ran with __syncthreads semantics (MfmaUtil pinned
// at ~40% regardless of pipeline depth; counted VMW dead code).
// Fix (m201/m218 template, the one that measured +38-73% counted-vs-drain):
//   BAR()  = __builtin_amdgcn_s_barrier()        (raw builtin, no drain)
//   VMW(n) = asm volatile("s_waitcnt vmcnt(n)")  (no clobber)
// Stage schedule (steady tile kt, buf c=kt&1):
//   P0: rd a23(c)   | stage A(kt+1)h0 | SBAR | MM(i01) | BAR
//   P1: rd a45(c)   | stage A(kt+1)h1 | SBAR | MM(i23) | BAR
//   P2: rd a67(c)   | stage B(kt+2)h0 | SBAR | MM(i45) | VMW(2) | BAR
//   P3: rd B(kt+1)+a01(c^1) | stage B(kt+2)h1 | SBAR | MM(i67) | BAR
// VMW(2) at P2-end completes A(kt+1)+B(kt+1) (consumed only after the
// following barrier), leaves B(kt+2)h0 in flight — never drains to 0 in
// steady state.

typedef unsigned short u16;
typedef u16    u16x8  __attribute__((ext_vector_type(8)));
typedef __bf16 bfv8   __attribute__((ext_vector_type(8)));
typedef float  f32x4  __attribute__((ext_vector_type(4)));

#define K_DIM 4096
#define N_DIM 11008
#define GS    128
#define KT64  (K_DIM / 64)   // 64 k-tiles of 64
#define LSTR  72             // fused-fallback padded LDS stride

__device__ __forceinline__ u16 f2bf(float f) {  // RTNE f32 -> bf16 bits
  union { float f; uint32_t u; } v;
  v.f = f;
  uint32_t u = v.u + 0x7FFFu + ((v.u >> 16) & 1u);
  return (u16)(u >> 16);
}
__device__ __forceinline__ float f16r(float v) {  // fp16 round-trip (RTNE)
  return (float)(_Float16)v;
}
__device__ __forceinline__ void async_load16(const u16* g, u16* l) {
  __builtin_amdgcn_global_load_lds(
      (const __attribute__((address_space(1))) uint32_t*)g,
      (__attribute__((address_space(3))) uint32_t*)l, 16, 0, 0);
}

// ---------------------------------------------------------------------------
// Pre-pass A: x f32 -> bf16 bits, [128][64] tiles, XOR-swizzled granules.
// granule g: row nl=g>>3, k-granule cg=(g&7)^(nl&7). Sequential 16B writes.
// ---------------------------------------------------------------------------
__global__ __launch_bounds__(256) void convert_x_tiled(
    const float* __restrict__ x, u16* __restrict__ xb) {
  const int kt = blockIdx.x, mt = blockIdx.y;
  const int k0 = kt * 64, m0 = mt * 128;
  u16* dst = xb + ((size_t)(mt * KT64 + kt)) * 8192;
#pragma unroll
  for (int i = 0; i < 4; ++i) {
    const int g  = i * 256 + threadIdx.x;
    const int nl = g >> 3;
    const int cg = (g & 7) ^ (nl & 7);
    const float* sp = x + (size_t)(m0 + nl) * K_DIM + (k0 + cg * 8);
    const f32x4 p = *(const f32x4*)sp;
    const f32x4 q = *(const f32x4*)(sp + 4);
    u16x8 o;
#pragma unroll
    for (int t = 0; t < 4; ++t) { o[t] = f2bf(p[t]); o[t + 4] = f2bf(q[t]); }
    *(u16x8*)(dst + (size_t)g * 8) = o;
  }
}

// ---------------------------------------------------------------------------
// Pre-pass B: dequantize int4 -> Wt bf16 bits, [128][64] tiles, SAME XOR
// swizzle. One granule = one qweight int32 (8 nibbles along K).
// ---------------------------------------------------------------------------
__global__ __launch_bounds__(256) void dequant_tiled(
    const uint32_t* __restrict__ qweight, const uint32_t* __restrict__ qzeros,
    const float* __restrict__ scales, u16* __restrict__ wt) {
  const int kt = blockIdx.x, nt = blockIdx.y;
  const int n0 = nt * 128;
  const int gq = kt >> 1;                       // quant group = kt*64/128
  u16* dst = wt + ((size_t)(nt * KT64 + kt)) * 8192;
#pragma unroll
  for (int i = 0; i < 4; ++i) {
    const int g  = i * 256 + threadIdx.x;
    const int nl = g >> 3;
    const int cg = (g & 7) ^ (nl & 7);
    const int n  = n0 + nl;
    const uint32_t zq = qzeros[(size_t)gq * (N_DIM / 8) + (n >> 3)];
    const int   z   = (int)((zq >> ((n & 7) * 4)) & 15u);
    const float s   = scales[(size_t)gq * N_DIM + n];
    const float nzs = -s * (float)z;            // w = fma(q,s,-z*s): exact in f32
    const uint32_t q = qweight[(size_t)(kt * 8 + cg) * N_DIM + n];
    u16x8 o;
#pragma unroll
    for (int t = 0; t < 8; ++t) {
      const int qv = (int)((q >> (t * 4)) & 15u);
      o[t] = f2bf(fmaf((float)qv, s, nzs));
    }
    *(u16x8*)(dst + (size_t)g * 8) = o;
  }
}

// ---------------------------------------------------------------------------
// GEMM: 256x256 tile, BK=64, 8 waves (2M x 4N), per-wave 128x64 (8x4 frags).
// ---------------------------------------------------------------------------
#define LDF(p)  __builtin_bit_cast(bfv8, *(const u16x8*)(p))
#define BAR()   __builtin_amdgcn_s_barrier()
#define VMW_(n) asm volatile("s_waitcnt vmcnt(" #n ")")
#define VMW(n)  VMW_(n)
#define SBAR()  __builtin_amdgcn_sched_barrier(0)

// stage half-tile h of A/B K-tile ktt into buffer (ktt & 1)
#define STAGE_AH(ktt, h) do {                                                 \
    const u16* s_ = at0 + ((size_t)(h) * KT64 + (ktt)) * 8192;                \
    u16* d_ = &As[(((ktt) & 1) * 16384) + (h) * 8192 + wave * 512];           \
    async_load16(s_ + (size_t)tid * 8, d_);                                   \
    async_load16(s_ + (size_t)(512 + tid) * 8, d_ + 4096);                    \
  } while (0)
#define STAGE_BH(ktt, h) do {                                                 \
    const u16* s_ = bt0 + ((size_t)(h) * KT64 + (ktt)) * 8192;                \
    u16* d_ = &Bs[(((ktt) & 1) * 16384) + (h) * 8192 + wave * 512];           \
    async_load16(s_ + (size_t)tid * 8, d_);                                   \
    async_load16(s_ + (size_t)(512 + tid) * 8, d_ + 4096);                    \
  } while (0)

// read A fragment pair {ib, ib+1} x {ks0, ks1} from buffer sbx
#define RD_AP(v, ib, sbx) do {                                                \
    v[0] = LDF(&As[(sbx) * 16384 + aoff + (ib) * 1024 + kq0]);                \
    v[1] = LDF(&As[(sbx) * 16384 + aoff + (ib) * 1024 + kq1]);                \
    v[2] = LDF(&As[(sbx) * 16384 + aoff + ((ib) + 1) * 1024 + kq0]);          \
    v[3] = LDF(&As[(sbx) * 16384 + aoff + ((ib) + 1) * 1024 + kq1]);          \
  } while (0)
// read all 8 B fragments (j 0..3 x ks 0..1) from buffer sbx
#define RD_B8(v, sbx) do {                                                    \
    _Pragma("unroll")                                                         \
    for (int j_ = 0; j_ < 4; ++j_) {                                          \
      v[2 * j_]     = LDF(&Bs[(sbx) * 16384 + boff + j_ * 1024 + kq0]);       \
      v[2 * j_ + 1] = LDF(&Bs[(sbx) * 16384 + boff + j_ * 1024 + kq1]);       \
    }                                                                         \
  } while (0)

// 16 MFMA for i-pair {ib, ib+1}: all j, both ks (dependent pairs 8 apart)
#define MM(ib, av, bv) do {                                                   \
    __builtin_amdgcn_s_setprio(1);                                            \
    _Pragma("unroll")                                                         \
    for (int ks_ = 0; ks_ < 2; ++ks_)                                         \
      _Pragma("unroll")                                                       \
      for (int ii_ = 0; ii_ < 2; ++ii_)                                       \
        _Pragma("unroll")                                                     \
        for (int j_ = 0; j_ < 4; ++j_)                                        \
          acc[(ib) + ii_][j_] = __builtin_amdgcn_mfma_f32_16x16x32_bf16(      \
              av[2 * ii_ + ks_], bv[2 * j_ + ks_], acc[(ib) + ii_][j_],       \
              0, 0, 0);                                                       \
    __builtin_amdgcn_s_setprio(0);                                            \
  } while (0)

// One K-tile, 4 phases. VMWSTMT is the P2-end wait statement.
#define KTILE(kt, bcur, bnxt, DO_STA, DO_STB, DO_NEXT, VMWSTMT) do {          \
    const int sb_ = (kt) & 1;                                                 \
    /* P0 */                                                                  \
    RD_AP(a23, 2, sb_);                                                       \
    if (DO_STA) { STAGE_AH((kt) + 1, 0); }                                    \
    SBAR();                                                                   \
    MM(0, a01, bcur);                                                         \
    BAR();                                                                    \
    /* P1 */                                                                  \
    RD_AP(a45, 4, sb_);                                                       \
    if (DO_STA) { STAGE_AH((kt) + 1, 1); }                                    \
    SBAR();                                                                   \
    MM(2, a23, bcur);                                                         \
    BAR();                                                                    \
    /* P2 */                                                                  \
    RD_AP(a67, 6, sb_);                                                       \
    if (DO_STB) { STAGE_BH((kt) + 2, 0); }                                    \
    SBAR();                                                                   \
    MM(4, a45, bcur);                                                         \
    VMWSTMT;                                                                  \
    BAR();                                                                    \
    /* P3 */                                                                  \
    if (DO_NEXT) { RD_B8(bnxt, sb_ ^ 1); RD_AP(a01, 0, sb_ ^ 1); }            \
    if (DO_STB) { STAGE_BH((kt) + 2, 1); }                                    \
    SBAR();                                                                   \
    MM(6, a67, bcur);                                                         \
    BAR();                                                                    \
  } while (0)

__global__ __launch_bounds__(512, 2) void gemm_256(
    const u16* __restrict__ xb, const u16* __restrict__ wt,
    const float* __restrict__ bias, float* __restrict__ out) {
  __shared__ __align__(16) u16 As[2 * 16384];   // 2 bufs x 2 halves x 8192
  __shared__ __align__(16) u16 Bs[2 * 16384];

  const int tid  = threadIdx.x;
  const int lane = tid & 63;
  const int wave = tid >> 6;
  const int wm   = wave >> 2;        // 0..1  (M)
  const int wn   = wave & 3;         // 0..3  (N)
  const int lrow = lane & 15;
  const int lk   = lane >> 4;        // k-quad 0..3
  const int swz  = lrow & 7;

  // XCD-aware bijective block swizzle (valid when nwg % 8 == 0)
  const int nwg = gridDim.x * gridDim.y;
  int wg = blockIdx.y * gridDim.x + blockIdx.x;
  if ((nwg & 7) == 0) wg = (wg & 7) * (nwg >> 3) + (wg >> 3);
  const int bx = wg % gridDim.x;
  const int by = wg / gridDim.x;
  const int n0 = bx * 256;
  const int m0 = by * 256;

  const u16* at0 = xb + (size_t)(2 * by) * KT64 * 8192;
  const u16* bt0 = wt + (size_t)(2 * bx) * KT64 * 8192;

  const int aoff = wm * 8192 + lrow * 64;
  const int boff = (wn >> 1) * 8192 + ((wn & 1) * 64 + lrow) * 64;
  const int kq0  = (lk ^ swz) * 8;
  const int kq1  = ((4 + lk) ^ swz) * 8;

  bfv8 a01[4], a23[4], a45[4], a67[4], bA[8], bB[8];
  f32x4 acc[8][4];
#pragma unroll
  for (int i = 0; i < 8; ++i)
#pragma unroll
    for (int j = 0; j < 4; ++j) acc[i][j] = f32x4{0.f, 0.f, 0.f, 0.f};

  // prologue: stage B(0), A(0), B(1), A(1) (16 loads). VMW(8) completes
  // B(0)+A(0), leaves B(1)+A(1) in flight — matches steady invariant
  // (tile 0's VMW(2) then completes B(1)+A(1), leaving B(2)h0).
  STAGE_BH(0, 0); STAGE_BH(0, 1); STAGE_AH(0, 0); STAGE_AH(0, 1);
  STAGE_BH(1, 0); STAGE_BH(1, 1); STAGE_AH(1, 0); STAGE_AH(1, 1);
  VMW(8); BAR();
  RD_B8(bA, 0); RD_AP(a01, 0, 0);    // lookahead reads for tile 0 P0

  // tile 0: A(1) already staged in prologue (DO_STA=0); stages B(2)
  KTILE(0, bA, bB, 0, 1, 1, VMW(2));

#pragma unroll 1
  for (int kt2 = 0; kt2 < 30; ++kt2) {   // tiles 1..60, steady state
    const int kt = 2 * kt2 + 1;
    KTILE(kt,     bB, bA, 1, 1, 1, VMW(2));
    KTILE(kt + 1, bA, bB, 1, 1, 1, VMW(2));
  }
  // tile 61 (bB): stages A(62), B(63); steady VMW(2)
  KTILE(61, bB, bA, 1, 1, 1, VMW(2));
  // tile 62 (bA): stages A(63) only; drain all at P2-end (1-phase cover)
  KTILE(62, bA, bB, 1, 0, 1, VMW(0));
  // tile 63 (bB): pure compute
  KTILE(63, bB, bA, 0, 0, 0, (void)0);

  // epilogue: ref rounding f16(f16(acc) + bias); store f32.
  // C/D layout (m89): col = lane&15, row = (lane>>4)*4 + reg
#pragma unroll
  for (int j = 0; j < 4; ++j) {
    const int n = n0 + wn * 64 + j * 16 + lrow;
    const float bvf = bias[n];
#pragma unroll
    for (int i = 0; i < 8; ++i) {
      const int mrow = m0 + wm * 128 + i * 16 + lk * 4;
#pragma unroll
      for (int r = 0; r < 4; ++r) {
        out[(size_t)(mrow + r) * N_DIM + n] = f16r(f16r(acc[i][j][r]) + bvf);
      }
    }
  }
}

// ---------------------------------------------------------------------------
// Fused fallback (no workspace / odd M): R4 structure, register staging.
// ---------------------------------------------------------------------------
__global__ __launch_bounds__(256) void gemm_fused(
    const float* __restrict__ xf, const uint32_t* __restrict__ qw,
    const uint32_t* __restrict__ qzeros, const float* __restrict__ scales,
    const float* __restrict__ bias, float* __restrict__ out) {
  __shared__ __align__(16) u16 As[128 * LSTR];
  __shared__ __align__(16) u16 Bs[128 * LSTR];

  const int tid  = threadIdx.x;
  const int lane = tid & 63;
  const int wave = tid >> 6;
  const int n0 = blockIdx.x * 128;
  const int m0 = blockIdx.y * 128;
  const int m_off = (wave >> 1) * 64;
  const int n_off = (wave & 1) * 64;
  const int lrow  = lane & 15;
  const int lk    = lane >> 4;
  const int sm = tid >> 3;
  const int sc = tid & 7;

  f32x4 acc[4][4];
#pragma unroll
  for (int i = 0; i < 4; ++i)
#pragma unroll
    for (int j = 0; j < 4; ++j) acc[i][j] = f32x4{0.f, 0.f, 0.f, 0.f};

  const int ncol = n0 + (tid & 127);
  float s_cur = 0.f, nzs_cur = 0.f;

  for (int kt = 0; kt < K_DIM / 64; ++kt) {
    const int k0 = kt * 64;
    u16x8 av[4];
#pragma unroll
    for (int i = 0; i < 4; ++i) {
      const int m = i * 32 + sm;
      const float* sp = xf + (size_t)(m0 + m) * K_DIM + (k0 + sc * 8);
      const f32x4 p = *(const f32x4*)sp;
      const f32x4 q4 = *(const f32x4*)(sp + 4);
#pragma unroll
      for (int t = 0; t < 4; ++t) { av[i][t] = f2bf(p[t]); av[i][t+4] = f2bf(q4[t]); }
    }
    u16x8 bv[4];
    if ((k0 & (GS - 1)) == 0) {
      const int g = k0 >> 7;
      const uint32_t zq = qzeros[(size_t)g * (N_DIM / 8) + (ncol >> 3)];
      const int z = (int)((zq >> ((ncol & 7) * 4)) & 15u);
      s_cur = scales[(size_t)g * N_DIM + ncol];
      nzs_cur = -s_cur * (float)z;
    }
#pragma unroll
    for (int i = 0; i < 4; ++i) {
      const int k8l = (tid >> 7) + i * 2;
      const uint32_t q = qw[(size_t)(k0 / 8 + k8l) * N_DIM + ncol];
#pragma unroll
      for (int t = 0; t < 8; ++t) {
        const int qv = (int)((q >> (t * 4)) & 15u);
        bv[i][t] = f2bf(fmaf((float)qv, s_cur, nzs_cur));
      }
    }
#pragma unroll
    for (int i = 0; i < 4; ++i)
      *(u16x8*)&As[(i * 32 + sm) * LSTR + sc * 8] = av[i];
    {
      const int nl = tid & 127;
#pragma unroll
      for (int i = 0; i < 4; ++i) {
        const int k8l = (tid >> 7) + i * 2;
        *(u16x8*)&Bs[nl * LSTR + k8l * 8] = bv[i];
      }
    }
    __syncthreads();
#pragma unroll
    for (int ks = 0; ks < 2; ++ks) {
      const int c = (ks * 4 + lk) * 8;
      bfv8 a[4], b[4];
#pragma unroll
      for (int i = 0; i < 4; ++i)
        a[i] = __builtin_bit_cast(bfv8,
                 *(const u16x8*)&As[(m_off + i * 16 + lrow) * LSTR + c]);
#pragma unroll
      for (int j = 0; j < 4; ++j)
        b[j] = __builtin_bit_cast(bfv8,
                 *(const u16x8*)&Bs[(n_off + j * 16 + lrow) * LSTR + c]);
#pragma unroll
      for (int i = 0; i < 4; ++i)
#pragma unroll
        for (int j = 0; j < 4; ++j)
          acc[i][j] = __builtin_amdgcn_mfma_f32_16x16x32_bf16(a[i], b[j],
                                                              acc[i][j], 0, 0, 0);
    }
    __syncthreads();
  }
#pragma unroll
  for (int j = 0; j < 4; ++j) {
    const int n = n0 + n_off + j * 16 + lrow;
    const float bvf = bias[n];
#pragma unroll
    for (int i = 0; i < 4; ++i) {
      const int mrow = m0 + m_off + i * 16 + lk * 4;
#pragma unroll
      for (int r = 0; r < 4; ++r)
        out[(size_t)(mrow + r) * N_DIM + n] = f16r(f16r(acc[i][j][r]) + bvf);
    }
  }
}

extern "C" void kernel_launch(void* const* d_in, const int* in_sizes, int n_in,
                              void* d_out, int out_size, void* d_ws, size_t ws_size,
                              hipStream_t stream) {
  // Identify inputs by element count (all five distinct).
  const float* x = nullptr;      const uint32_t* qweight = nullptr;
  const uint32_t* qzeros = nullptr;
  const float* scales = nullptr; const float* bias = nullptr;
  int M = 4096;
  for (int i = 0; i < n_in; ++i) {
    const long long s = in_sizes[i];
    if      (s == (long long)(K_DIM / 8) * N_DIM) qweight = (const uint32_t*)d_in[i];
    else if (s == (long long)(K_DIM / GS) * (N_DIM / 8)) qzeros = (const uint32_t*)d_in[i];
    else if (s == (long long)(K_DIM / GS) * N_DIM) scales = (const float*)d_in[i];
    else if (s == (long long)N_DIM) bias = (const float*)d_in[i];
    else { x = (const float*)d_in[i]; M = (int)(s / K_DIM); }
  }
  float* out = (float*)d_out;

  const size_t xb_bytes = (size_t)M * K_DIM * sizeof(u16);      // 33.5 MB
  const size_t wt_bytes = (size_t)N_DIM * K_DIM * sizeof(u16);  // 90.2 MB

  if (ws_size >= xb_bytes + wt_bytes && (M % 256) == 0) {
    u16* xbp = (u16*)d_ws;
    u16* wtp = (u16*)((char*)d_ws + xb_bytes);
    convert_x_tiled<<<dim3(KT64, M / 128), 256, 0, stream>>>(x, xbp);
    dequant_tiled<<<dim3(KT64, N_DIM / 128), 256, 0, stream>>>(
        qweight, qzeros, scales, wtp);
    gemm_256<<<dim3(N_DIM / 256, M / 256), 512, 0, stream>>>(
        xbp, wtp, bias, out);
  } else {
    gemm_fused<<<dim3(N_DIM / 128, (M + 127) / 128), 256, 0, stream>>>(
        x, qweight, qzeros, scales, bias, out);
  }
}